// Round 1
// baseline (583.966 us; speedup 1.0000x reference)
//
#include <hip/hip_runtime.h>
#include <cstddef>

#define GG 2048
#define PP 18
#define NNODE (GG*PP)      // 36864
#define EPG 306            // directed edges per graph (17*18)
#define F1 128             // H1*C1
#define F2 256             // H2*C2
#define H1n 4
#define C1n 32
#define H2n 4
#define C2n 64
#define INF 6

__device__ __forceinline__ float lrelu(float v) { return v > 0.f ? v : 0.01f * v; }

// ---------------- layer 1: GATv2 (6 -> 4x32), one block per graph ----------------
__global__ __launch_bounds__(256) void gat1_kernel(
    const float* __restrict__ x, const float* __restrict__ eattr,
    const float* __restrict__ W1l, const float* __restrict__ b1l,
    const float* __restrict__ W1r, const float* __restrict__ b1r,
    const float* __restrict__ We1, const float* __restrict__ att1,
    const float* __restrict__ bias1, float* __restrict__ h1)
{
    __shared__ float xs[PP*INF];
    __shared__ float wl[INF*F1], wr[INF*F1];
    __shared__ float bl[F1], br[F1], we[F1], att[F1];
    __shared__ float ea[PP*PP];            // ea[s*18+d]
    __shared__ float xl[PP*F1], xr[PP*F1];
    __shared__ float alpha[PP*PP*H1n];     // [d][s][h]
    const int g = blockIdx.x, tid = threadIdx.x;

    if (tid < PP*INF) xs[tid] = x[g*PP*INF + tid];
    for (int i = tid; i < INF*F1; i += 256) { wl[i] = W1l[i]; wr[i] = W1r[i]; }
    if (tid < F1) { bl[tid]=b1l[tid]; br[tid]=b1r[tid]; we[tid]=We1[tid]; att[tid]=att1[tid]; }
    for (int t = tid; t < EPG; t += 256) {
        int s = t/17, pos = t%17;
        int d = pos + (pos >= s);
        ea[s*PP + d] = eattr[g*EPG + t];
    }
    __syncthreads();
    if (tid < PP) {   // self-loop attr = mean of incoming
        float sum = 0.f;
        for (int s = 0; s < PP; ++s) if (s != tid) sum += ea[s*PP + tid];
        ea[tid*PP + tid] = sum * (1.f/17.f);
    }
    __syncthreads();
    // projections xl = x@Wl+bl, xr = x@Wr+br
    for (int o = tid; o < PP*F1; o += 256) {
        int n = o >> 7, j = o & (F1-1);
        float al = bl[j], ar = br[j];
        #pragma unroll
        for (int k = 0; k < INF; ++k) {
            float xv = xs[n*INF + k];
            al = fmaf(xv, wl[k*F1 + j], al);
            ar = fmaf(xv, wr[k*F1 + j], ar);
        }
        xl[o] = al; xr[o] = ar;
    }
    __syncthreads();
    // alpha[d][s][h] = sum_c lrelu(xl[s]+xr[d]+ea*We)[h,c] * att[h,c]
    for (int t = tid; t < PP*PP*H1n; t += 256) {
        int h = t & 3, s = (t >> 2) % PP, d = t / (PP*H1n);
        float eav = ea[s*PP + d];
        int j0 = h*C1n;
        float acc = 0.f;
        for (int cc = 0; cc < C1n; ++cc) {
            int c = (cc + tid) & (C1n-1);   // rotate to spread LDS banks
            float v = lrelu(xl[s*F1 + j0 + c] + xr[d*F1 + j0 + c] + eav*we[j0 + c]);
            acc = fmaf(v, att[j0 + c], acc);
        }
        alpha[t] = acc;
    }
    __syncthreads();
    // softmax over s per (d,h)
    if (tid < PP*H1n) {
        int d = tid >> 2, h = tid & 3;
        int base = d*(PP*H1n) + h;
        float m = -1e30f;
        for (int s = 0; s < PP; ++s) m = fmaxf(m, alpha[base + s*H1n]);
        float sum = 0.f;
        for (int s = 0; s < PP; ++s) sum += __expf(alpha[base + s*H1n] - m);
        float inv = 1.f/(sum + 1e-16f);
        for (int s = 0; s < PP; ++s)
            alpha[base + s*H1n] = __expf(alpha[base + s*H1n] - m) * inv;
    }
    __syncthreads();
    // out[d] = sum_s a[d,s] * xl[s]  (+bias)
    for (int o = tid; o < PP*F1; o += 256) {
        int d = o >> 7, j = o & (F1-1), h = j >> 5;
        float acc = bias1[j];
        for (int s = 0; s < PP; ++s)
            acc = fmaf(alpha[d*(PP*H1n) + s*H1n + h], xl[s*F1 + j], acc);
        h1[(size_t)g*(PP*F1) + o] = acc;
    }
}

// ---------------- BN stats: per-column sum & sumsq via atomics ----------------
__global__ void bnstats(const float* __restrict__ h, float* __restrict__ sum,
                        float* __restrict__ ss, int C, int rowsPerBlock)
{
    int col = threadIdx.x;                 // blockDim.x == C
    size_t r0 = (size_t)blockIdx.x * rowsPerBlock;
    float s = 0.f, q = 0.f;
    for (int r = 0; r < rowsPerBlock; ++r) {
        float v = h[(r0 + r)*(size_t)C + col];
        s += v; q = fmaf(v, v, q);
    }
    atomicAdd(&sum[col], s);
    atomicAdd(&ss[col], q);
}

__global__ void bnfin(const float* __restrict__ sum, const float* __restrict__ ss,
                      const float* __restrict__ gamma, const float* __restrict__ beta,
                      float* __restrict__ sc, float* __restrict__ sh, int C, float invN)
{
    int c = threadIdx.x + blockIdx.x*blockDim.x;
    if (c < C) {
        float mu = sum[c]*invN;
        float var = ss[c]*invN - mu*mu;
        float s = gamma[c]*rsqrtf(var + 1e-5f);
        sc[c] = s;
        sh[c] = beta[c] - mu*s;
    }
}

__global__ void zero_kernel(float* __restrict__ p, int n) {
    int i = blockIdx.x*blockDim.x + threadIdx.x;
    if (i < n) p[i] = 0.f;
}

// ---------------- layer 2: GATv2 (128 -> 4x64), one block per graph ----------------
__global__ __launch_bounds__(256) void gat2_kernel(
    const float* __restrict__ h1, const float* __restrict__ eattr,
    const float* __restrict__ sc1, const float* __restrict__ sh1,
    const float* __restrict__ W2l, const float* __restrict__ b2l,
    const float* __restrict__ W2r, const float* __restrict__ b2r,
    const float* __restrict__ We2, const float* __restrict__ att2,
    const float* __restrict__ bias2, float* __restrict__ h2)
{
    __shared__ float hin[PP*F1];           // bn+lrelu(h1)
    __shared__ float ea[PP*PP];
    __shared__ float xl[PP*F2], xr[PP*F2];
    __shared__ float alpha[PP*PP*H2n];
    __shared__ float we[F2], att[F2], sc[F1], sh[F1];
    const int g = blockIdx.x, tid = threadIdx.x;

    if (tid < F1) { sc[tid] = sc1[tid]; sh[tid] = sh1[tid]; }
    if (tid < F2) { we[tid] = We2[tid]; att[tid] = att2[tid]; }
    for (int t = tid; t < EPG; t += 256) {
        int s = t/17, pos = t%17;
        int d = pos + (pos >= s);
        ea[s*PP + d] = eattr[g*EPG + t];
    }
    __syncthreads();
    for (int i = tid; i < PP*F1; i += 256) {
        int c = i & (F1-1);
        hin[i] = lrelu(fmaf(sc[c], h1[(size_t)g*(PP*F1) + i], sh[c]));
    }
    if (tid < PP) {
        float sum = 0.f;
        for (int s = 0; s < PP; ++s) if (s != tid) sum += ea[s*PP + tid];
        ea[tid*PP + tid] = sum * (1.f/17.f);
    }
    __syncthreads();
    // projections: 18x128 @ 128x256 (x2), register-tiled:
    // wave gq owns rows {gq, gq+4, gq+8, ...}; thread owns 4 consecutive cols
    const int gq = tid >> 6;
    const int j0 = (tid & 63) << 2;
    const int nrows = (21 - gq) >> 2;      // 5,5,4,4
    {
        float acc[5][4];
        float4 b4 = *reinterpret_cast<const float4*>(&b2l[j0]);
        #pragma unroll
        for (int rr = 0; rr < 5; ++rr) { acc[rr][0]=b4.x; acc[rr][1]=b4.y; acc[rr][2]=b4.z; acc[rr][3]=b4.w; }
        for (int k = 0; k < F1; ++k) {
            float4 w4 = *reinterpret_cast<const float4*>(&W2l[k*F2 + j0]);
            #pragma unroll
            for (int rr = 0; rr < 5; ++rr) {
                if (rr < nrows) {
                    float hv = hin[(gq + (rr<<2))*F1 + k];
                    acc[rr][0] = fmaf(hv, w4.x, acc[rr][0]);
                    acc[rr][1] = fmaf(hv, w4.y, acc[rr][1]);
                    acc[rr][2] = fmaf(hv, w4.z, acc[rr][2]);
                    acc[rr][3] = fmaf(hv, w4.w, acc[rr][3]);
                }
            }
        }
        #pragma unroll
        for (int rr = 0; rr < 5; ++rr) if (rr < nrows) {
            int n = gq + (rr<<2);
            *reinterpret_cast<float4*>(&xl[n*F2 + j0]) = make_float4(acc[rr][0],acc[rr][1],acc[rr][2],acc[rr][3]);
        }
        float4 c4 = *reinterpret_cast<const float4*>(&b2r[j0]);
        #pragma unroll
        for (int rr = 0; rr < 5; ++rr) { acc[rr][0]=c4.x; acc[rr][1]=c4.y; acc[rr][2]=c4.z; acc[rr][3]=c4.w; }
        for (int k = 0; k < F1; ++k) {
            float4 w4 = *reinterpret_cast<const float4*>(&W2r[k*F2 + j0]);
            #pragma unroll
            for (int rr = 0; rr < 5; ++rr) {
                if (rr < nrows) {
                    float hv = hin[(gq + (rr<<2))*F1 + k];
                    acc[rr][0] = fmaf(hv, w4.x, acc[rr][0]);
                    acc[rr][1] = fmaf(hv, w4.y, acc[rr][1]);
                    acc[rr][2] = fmaf(hv, w4.z, acc[rr][2]);
                    acc[rr][3] = fmaf(hv, w4.w, acc[rr][3]);
                }
            }
        }
        #pragma unroll
        for (int rr = 0; rr < 5; ++rr) if (rr < nrows) {
            int n = gq + (rr<<2);
            *reinterpret_cast<float4*>(&xr[n*F2 + j0]) = make_float4(acc[rr][0],acc[rr][1],acc[rr][2],acc[rr][3]);
        }
    }
    __syncthreads();
    for (int t = tid; t < PP*PP*H2n; t += 256) {
        int h = t & 3, s = (t >> 2) % PP, d = t / (PP*H2n);
        float eav = ea[s*PP + d];
        int ja = h*C2n;
        float acc = 0.f;
        for (int cc = 0; cc < C2n; ++cc) {
            int c = (cc + tid) & (C2n-1);
            float v = lrelu(xl[s*F2 + ja + c] + xr[d*F2 + ja + c] + eav*we[ja + c]);
            acc = fmaf(v, att[ja + c], acc);
        }
        alpha[t] = acc;
    }
    __syncthreads();
    if (tid < PP*H2n) {
        int d = tid >> 2, h = tid & 3;
        int base = d*(PP*H2n) + h;
        float m = -1e30f;
        for (int s = 0; s < PP; ++s) m = fmaxf(m, alpha[base + s*H2n]);
        float sum = 0.f;
        for (int s = 0; s < PP; ++s) sum += __expf(alpha[base + s*H2n] - m);
        float inv = 1.f/(sum + 1e-16f);
        for (int s = 0; s < PP; ++s)
            alpha[base + s*H2n] = __expf(alpha[base + s*H2n] - m) * inv;
    }
    __syncthreads();
    for (int o = tid; o < PP*F2; o += 256) {
        int d = o >> 8, j = o & (F2-1), h = j >> 6;
        float acc = bias2[j];
        for (int s = 0; s < PP; ++s)
            acc = fmaf(alpha[d*(PP*H2n) + s*H2n + h], xl[s*F2 + j], acc);
        h2[(size_t)g*(PP*F2) + o] = acc;
    }
}

// ---------------- BN2+lrelu + mean-pool + MLP head, one block per graph ----------------
__global__ __launch_bounds__(256) void mlp_kernel(
    const float* __restrict__ h2, const float* __restrict__ sc2, const float* __restrict__ sh2,
    const float* __restrict__ Wfc1, const float* __restrict__ bfc1,
    const float* __restrict__ Wfc2, const float* __restrict__ bfc2,
    const float* __restrict__ Wfc3, const float* __restrict__ bfc3,
    float* __restrict__ out)
{
    __shared__ float pooled[F2];
    __shared__ float y1[512];
    __shared__ float y2[128];
    const int g = blockIdx.x, tid = threadIdx.x;
    if (tid < F2) {
        float s = 0.f;
        float scv = sc2[tid], shv = sh2[tid];
        for (int n = 0; n < PP; ++n) {
            float v = fmaf(scv, h2[(size_t)g*(PP*F2) + n*F2 + tid], shv);
            s += lrelu(v);
        }
        pooled[tid] = s * (1.f/18.f);
    }
    __syncthreads();
    for (int j = tid; j < 512; j += 256) {
        float acc = bfc1[j];
        for (int k = 0; k < F2; ++k) acc = fmaf(pooled[k], Wfc1[k*512 + j], acc);
        y1[j] = lrelu(acc);
    }
    __syncthreads();
    if (tid < 128) {
        float acc = bfc2[tid];
        for (int k = 0; k < 512; ++k) acc = fmaf(y1[k], Wfc2[k*128 + tid], acc);
        y2[tid] = lrelu(acc) * Wfc3[tid];   // fuse fc3 elementwise product
    }
    __syncthreads();
    if (tid == 0) {
        float acc = bfc3[0];
        for (int k = 0; k < 128; ++k) acc += y2[k];
        out[g] = acc;
    }
}

extern "C" void kernel_launch(void* const* d_in, const int* in_sizes, int n_in,
                              void* d_out, int out_size, void* d_ws, size_t ws_size,
                              hipStream_t stream)
{
    const float* x     = (const float*)d_in[0];
    const float* eattr = (const float*)d_in[1];
    // d_in[2] edge_index, d_in[3] batch: structure is deterministic, not needed
    const float* W1l   = (const float*)d_in[4];
    const float* b1l   = (const float*)d_in[5];
    const float* W1r   = (const float*)d_in[6];
    const float* b1r   = (const float*)d_in[7];
    const float* We1   = (const float*)d_in[8];
    const float* att1  = (const float*)d_in[9];
    const float* bias1 = (const float*)d_in[10];
    const float* W2l   = (const float*)d_in[11];
    const float* b2l   = (const float*)d_in[12];
    const float* W2r   = (const float*)d_in[13];
    const float* b2r   = (const float*)d_in[14];
    const float* We2   = (const float*)d_in[15];
    const float* att2  = (const float*)d_in[16];
    const float* bias2 = (const float*)d_in[17];
    const float* g1    = (const float*)d_in[18];
    const float* be1   = (const float*)d_in[19];
    const float* g2    = (const float*)d_in[20];
    const float* be2   = (const float*)d_in[21];
    const float* Wfc1  = (const float*)d_in[22];
    const float* bfc1  = (const float*)d_in[23];
    const float* Wfc2  = (const float*)d_in[24];
    const float* bfc2  = (const float*)d_in[25];
    const float* Wfc3  = (const float*)d_in[26];
    const float* bfc3  = (const float*)d_in[27];
    float* out = (float*)d_out;

    float* ws = (float*)d_ws;
    float* h1 = ws;                                  // N*128
    float* h2 = h1 + (size_t)NNODE*F1;               // N*256
    float* st = h2 + (size_t)NNODE*F2;               // stats
    float* sum1 = st,        *ss1 = st+128, *sc1 = st+256,  *sh1 = st+384;
    float* sum2 = st+512,    *ss2 = st+768, *sc2 = st+1024, *sh2 = st+1280;

    zero_kernel<<<6, 256, 0, stream>>>(st, 1536);
    gat1_kernel<<<GG, 256, 0, stream>>>(x, eattr, W1l, b1l, W1r, b1r, We1, att1, bias1, h1);
    bnstats<<<288, 128, 0, stream>>>(h1, sum1, ss1, F1, 128);
    bnfin<<<1, 128, 0, stream>>>(sum1, ss1, g1, be1, sc1, sh1, F1, 1.f/NNODE);
    gat2_kernel<<<GG, 256, 0, stream>>>(h1, eattr, sc1, sh1, W2l, b2l, W2r, b2r, We2, att2, bias2, h2);
    bnstats<<<144, 256, 0, stream>>>(h2, sum2, ss2, F2, 256);
    bnfin<<<1, 256, 0, stream>>>(sum2, ss2, g2, be2, sc2, sh2, F2, 1.f/NNODE);
    mlp_kernel<<<GG, 256, 0, stream>>>(h2, sc2, sh2, Wfc1, bfc1, Wfc2, bfc2, Wfc3, bfc3, out);
}

// Round 2
// 331.577 us; speedup vs baseline: 1.7612x; 1.7612x over previous
//
#include <hip/hip_runtime.h>
#include <cstddef>

#define GG 2048
#define PP 18
#define NNODE (GG*PP)      // 36864
#define EPG 306            // directed edges per graph (17*18)
#define F1 128             // H1*C1
#define F2 256             // H2*C2
#define H1n 4
#define C1n 32
#define H2n 4
#define C2n 64
#define INF 6

typedef unsigned short u16;
typedef __attribute__((ext_vector_type(8))) short short8;   // 8 bf16 (4 VGPRs)
typedef __attribute__((ext_vector_type(4))) float f32x4;

__device__ __forceinline__ float lrelu(float v) { return v > 0.f ? v : 0.01f * v; }

__device__ __forceinline__ u16 f2b(float x) {            // fp32 -> bf16 RNE
    union { float f; unsigned u; } c; c.f = x;
    unsigned r = c.u + 0x7FFF + ((c.u >> 16) & 1);
    return (u16)(r >> 16);
}
__device__ __forceinline__ float b2f(u16 v) {
    union { unsigned u; float f; } c; c.u = ((unsigned)v) << 16;
    return c.f;
}

// ---------------- layer 1: GATv2 (6 -> 4x32), one block per graph ----------------
__global__ __launch_bounds__(256) void gat1_kernel(
    const float* __restrict__ x, const float* __restrict__ eattr,
    const float* __restrict__ W1l, const float* __restrict__ b1l,
    const float* __restrict__ W1r, const float* __restrict__ b1r,
    const float* __restrict__ We1, const float* __restrict__ att1,
    const float* __restrict__ bias1, float* __restrict__ h1)
{
    __shared__ float xs[PP*INF];
    __shared__ float wl[INF*F1], wr[INF*F1];
    __shared__ float bl[F1], br[F1], we[F1], att[F1];
    __shared__ float ea[PP*PP];            // ea[s*18+d]
    __shared__ float xl[PP*F1], xr[PP*F1];
    __shared__ float alpha[PP*PP*H1n];     // [d][s][h]
    const int g = blockIdx.x, tid = threadIdx.x;

    if (tid < PP*INF) xs[tid] = x[g*PP*INF + tid];
    for (int i = tid; i < INF*F1; i += 256) { wl[i] = W1l[i]; wr[i] = W1r[i]; }
    if (tid < F1) { bl[tid]=b1l[tid]; br[tid]=b1r[tid]; we[tid]=We1[tid]; att[tid]=att1[tid]; }
    for (int t = tid; t < EPG; t += 256) {
        int s = t/17, pos = t%17;
        int d = pos + (pos >= s);
        ea[s*PP + d] = eattr[g*EPG + t];
    }
    __syncthreads();
    if (tid < PP) {   // self-loop attr = mean of incoming
        float sum = 0.f;
        for (int s = 0; s < PP; ++s) if (s != tid) sum += ea[s*PP + tid];
        ea[tid*PP + tid] = sum * (1.f/17.f);
    }
    __syncthreads();
    for (int o = tid; o < PP*F1; o += 256) {
        int n = o >> 7, j = o & (F1-1);
        float al = bl[j], ar = br[j];
        #pragma unroll
        for (int k = 0; k < INF; ++k) {
            float xv = xs[n*INF + k];
            al = fmaf(xv, wl[k*F1 + j], al);
            ar = fmaf(xv, wr[k*F1 + j], ar);
        }
        xl[o] = al; xr[o] = ar;
    }
    __syncthreads();
    for (int t = tid; t < PP*PP*H1n; t += 256) {
        int h = t & 3, s = (t >> 2) % PP, d = t / (PP*H1n);
        float eav = ea[s*PP + d];
        int j0 = h*C1n;
        float acc = 0.f;
        for (int cc = 0; cc < C1n; ++cc) {
            int c = (cc + tid) & (C1n-1);
            float v = lrelu(xl[s*F1 + j0 + c] + xr[d*F1 + j0 + c] + eav*we[j0 + c]);
            acc = fmaf(v, att[j0 + c], acc);
        }
        alpha[t] = acc;
    }
    __syncthreads();
    if (tid < PP*H1n) {
        int d = tid >> 2, h = tid & 3;
        int base = d*(PP*H1n) + h;
        float m = -1e30f;
        for (int s = 0; s < PP; ++s) m = fmaxf(m, alpha[base + s*H1n]);
        float sum = 0.f;
        for (int s = 0; s < PP; ++s) sum += __expf(alpha[base + s*H1n] - m);
        float inv = 1.f/(sum + 1e-16f);
        for (int s = 0; s < PP; ++s)
            alpha[base + s*H1n] = __expf(alpha[base + s*H1n] - m) * inv;
    }
    __syncthreads();
    for (int o = tid; o < PP*F1; o += 256) {
        int d = o >> 7, j = o & (F1-1), h = j >> 5;
        float acc = bias1[j];
        for (int s = 0; s < PP; ++s)
            acc = fmaf(alpha[d*(PP*H1n) + s*H1n + h], xl[s*F1 + j], acc);
        h1[(size_t)g*(PP*F1) + o] = acc;
    }
}

// ---------------- BN stats ----------------
__global__ void bnstats(const float* __restrict__ h, float* __restrict__ sum,
                        float* __restrict__ ss, int C, int rowsPerBlock)
{
    int col = threadIdx.x;
    size_t r0 = (size_t)blockIdx.x * rowsPerBlock;
    float s = 0.f, q = 0.f;
    for (int r = 0; r < rowsPerBlock; ++r) {
        float v = h[(r0 + r)*(size_t)C + col];
        s += v; q = fmaf(v, v, q);
    }
    atomicAdd(&sum[col], s);
    atomicAdd(&ss[col], q);
}

__global__ void bnfin(const float* __restrict__ sum, const float* __restrict__ ss,
                      const float* __restrict__ gamma, const float* __restrict__ beta,
                      float* __restrict__ sc, float* __restrict__ sh, int C, float invN)
{
    int c = threadIdx.x + blockIdx.x*blockDim.x;
    if (c < C) {
        float mu = sum[c]*invN;
        float var = ss[c]*invN - mu*mu;
        float s = gamma[c]*rsqrtf(var + 1e-5f);
        sc[c] = s;
        sh[c] = beta[c] - mu*s;
    }
}

__global__ void zero_kernel(float* __restrict__ p, int n) {
    int i = blockIdx.x*blockDim.x + threadIdx.x;
    if (i < n) p[i] = 0.f;
}

// ---------------- prep: W2 -> bf16 transposed, bias concat ----------------
__global__ void prep_w(const float* __restrict__ W2l, const float* __restrict__ W2r,
                       const float* __restrict__ b2l, const float* __restrict__ b2r,
                       u16* __restrict__ wbt, float* __restrict__ biascat)
{
    int t = blockIdx.x*blockDim.x + threadIdx.x;
    if (t < 512*128) {
        int c = t >> 7, k = t & 127;
        float v = (c < 256) ? W2l[k*256 + c] : W2r[k*256 + (c-256)];
        wbt[t] = f2b(v);           // wbt[c][k]
    } else if (t < 512*128 + 512) {
        int c = t - 512*128;
        biascat[c] = (c < 256) ? b2l[c] : b2r[c-256];
    }
}

// ---------------- prep: hbf = bf16(lrelu(bn1(h1))) ----------------
__global__ void prep_hbf(const float* __restrict__ h1, const float* __restrict__ sc,
                         const float* __restrict__ sh, u16* __restrict__ hbf)
{
    int i4 = blockIdx.x*blockDim.x + threadIdx.x;
    if (i4 >= NNODE*F1/4) return;
    int i = i4 * 4, c = i & 127;
    float4 v = *reinterpret_cast<const float4*>(&h1[i]);
    ushort4 o;
    o.x = f2b(lrelu(fmaf(sc[c  ], v.x, sh[c  ])));
    o.y = f2b(lrelu(fmaf(sc[c+1], v.y, sh[c+1])));
    o.z = f2b(lrelu(fmaf(sc[c+2], v.z, sh[c+2])));
    o.w = f2b(lrelu(fmaf(sc[c+3], v.w, sh[c+3])));
    *reinterpret_cast<ushort4*>(&hbf[i]) = o;
}

// ---------------- layer-2 projection GEMM: (36864x128)bf16 @ (128x512)bf16 -> xlr bf16 ----------------
// 64x64 tile per block (4 waves, wave = 16 rows x 64 cols), K=128 in one LDS stage.
// Both A and B staged as [64][128] bf16 with XOR swizzle idx ^= (row&7)<<3 (byte<<4):
// 16-lane same-column ds_read_b128 spreads over 8 slots -> <=2-way conflict (free).
__global__ __launch_bounds__(256) void gemm2_kernel(
    const u16* __restrict__ hbf, const u16* __restrict__ wbt,
    const float* __restrict__ biascat, u16* __restrict__ xlr)
{
    __shared__ u16 As[64*128];
    __shared__ u16 Bs[64*128];
    const int b = blockIdx.x;
    const int bm = b >> 3, bn = b & 7;
    const int r0 = bm*64, c0 = bn*64;
    const int tid = threadIdx.x;

    for (int i = tid*8; i < 64*128; i += 256*8) {
        int r = i >> 7;
        int idx = i ^ ((r & 7) << 3);
        *reinterpret_cast<short8*>(&As[idx]) =
            *reinterpret_cast<const short8*>(&hbf[(size_t)(r0+r)*128 + (i & 127)]);
        *reinterpret_cast<short8*>(&Bs[idx]) =
            *reinterpret_cast<const short8*>(&wbt[(size_t)(c0+r)*128 + (i & 127)]);
    }
    __syncthreads();

    const int w = tid >> 6, l = tid & 63;
    const int lr = l & 15, lk = (l >> 4) * 8;
    const int ar = w*16 + lr;                  // A row this lane supplies
    f32x4 acc[4] = {f32x4{0,0,0,0}, f32x4{0,0,0,0}, f32x4{0,0,0,0}, f32x4{0,0,0,0}};

    #pragma unroll
    for (int kk = 0; kk < 4; ++kk) {
        int k0 = kk*32 + lk;
        short8 a = *reinterpret_cast<const short8*>(&As[(ar*128 + k0) ^ ((ar & 7) << 3)]);
        #pragma unroll
        for (int n = 0; n < 4; ++n) {
            int br = n*16 + lr;                // B col this lane supplies
            short8 bf = *reinterpret_cast<const short8*>(&Bs[(br*128 + k0) ^ ((br & 7) << 3)]);
            acc[n] = __builtin_amdgcn_mfma_f32_16x16x32_bf16(a, bf, acc[n], 0, 0, 0);
        }
    }
    // C/D layout: col = lane&15, row = (lane>>4)*4 + j   [m89-verified]
    const int rbase = r0 + w*16 + (l >> 4)*4;
    #pragma unroll
    for (int n = 0; n < 4; ++n) {
        int C = c0 + n*16 + lr;
        float bv = biascat[C];
        #pragma unroll
        for (int j = 0; j < 4; ++j) {
            xlr[(size_t)(rbase + j)*512 + C] = f2b(acc[n][j] + bv);
        }
    }
}

// ---------------- layer 2 attention (one block per graph) ----------------
__global__ __launch_bounds__(256) void gat2_attn(
    const u16* __restrict__ xlr, const float* __restrict__ eattr,
    const float* __restrict__ We2, const float* __restrict__ att2,
    const float* __restrict__ bias2, float* __restrict__ h2)
{
    __shared__ float xl[PP*F2], xr[PP*F2];
    __shared__ float ea[PP*PP];
    __shared__ float alpha[PP*PP*H2n];
    __shared__ float we[F2], att[F2];
    const int g = blockIdx.x, tid = threadIdx.x;

    if (tid < F2) { we[tid] = We2[tid]; att[tid] = att2[tid]; }
    for (int i4 = tid; i4 < PP*128; i4 += 256) {     // 18*512 elems in quads
        int i = i4*4, n = i >> 9, j = i & 511;
        ushort4 v = *reinterpret_cast<const ushort4*>(&xlr[(size_t)(g*PP + n)*512 + j]);
        float* dst = (j < 256) ? &xl[n*F2 + j] : &xr[n*F2 + j - 256];
        dst[0] = b2f(v.x); dst[1] = b2f(v.y); dst[2] = b2f(v.z); dst[3] = b2f(v.w);
    }
    for (int t = tid; t < EPG; t += 256) {
        int s = t/17, pos = t%17;
        int d = pos + (pos >= s);
        ea[s*PP + d] = eattr[g*EPG + t];
    }
    __syncthreads();
    if (tid < PP) {
        float sum = 0.f;
        for (int s = 0; s < PP; ++s) if (s != tid) sum += ea[s*PP + tid];
        ea[tid*PP + tid] = sum * (1.f/17.f);
    }
    __syncthreads();
    for (int t = tid; t < PP*PP*H2n; t += 256) {
        int h = t & 3, s = (t >> 2) % PP, d = t / (PP*H2n);
        float eav = ea[s*PP + d];
        int ja = h*C2n;
        float acc = 0.f;
        for (int cc = 0; cc < C2n; ++cc) {
            int c = (cc + tid) & (C2n-1);
            float v = lrelu(xl[s*F2 + ja + c] + xr[d*F2 + ja + c] + eav*we[ja + c]);
            acc = fmaf(v, att[ja + c], acc);
        }
        alpha[t] = acc;
    }
    __syncthreads();
    if (tid < PP*H2n) {
        int d = tid >> 2, h = tid & 3;
        int base = d*(PP*H2n) + h;
        float m = -1e30f;
        for (int s = 0; s < PP; ++s) m = fmaxf(m, alpha[base + s*H2n]);
        float sum = 0.f;
        for (int s = 0; s < PP; ++s) sum += __expf(alpha[base + s*H2n] - m);
        float inv = 1.f/(sum + 1e-16f);
        for (int s = 0; s < PP; ++s)
            alpha[base + s*H2n] = __expf(alpha[base + s*H2n] - m) * inv;
    }
    __syncthreads();
    for (int o = tid; o < PP*F2; o += 256) {
        int d = o >> 8, j = o & (F2-1), h = j >> 6;
        float acc = bias2[j];
        for (int s = 0; s < PP; ++s)
            acc = fmaf(alpha[d*(PP*H2n) + s*H2n + h], xl[s*F2 + j], acc);
        h2[(size_t)g*(PP*F2) + o] = acc;
    }
}

// ---------------- BN2+lrelu + mean-pool + MLP head ----------------
__global__ __launch_bounds__(256) void mlp_kernel(
    const float* __restrict__ h2, const float* __restrict__ sc2, const float* __restrict__ sh2,
    const float* __restrict__ Wfc1, const float* __restrict__ bfc1,
    const float* __restrict__ Wfc2, const float* __restrict__ bfc2,
    const float* __restrict__ Wfc3, const float* __restrict__ bfc3,
    float* __restrict__ out)
{
    __shared__ float pooled[F2];
    __shared__ float y1[512];
    __shared__ float y2[128];
    const int g = blockIdx.x, tid = threadIdx.x;
    if (tid < F2) {
        float s = 0.f;
        float scv = sc2[tid], shv = sh2[tid];
        for (int n = 0; n < PP; ++n) {
            float v = fmaf(scv, h2[(size_t)g*(PP*F2) + n*F2 + tid], shv);
            s += lrelu(v);
        }
        pooled[tid] = s * (1.f/18.f);
    }
    __syncthreads();
    for (int j = tid; j < 512; j += 256) {
        float acc = bfc1[j];
        for (int k = 0; k < F2; ++k) acc = fmaf(pooled[k], Wfc1[k*512 + j], acc);
        y1[j] = lrelu(acc);
    }
    __syncthreads();
    if (tid < 128) {
        float acc = bfc2[tid];
        for (int k = 0; k < 512; ++k) acc = fmaf(y1[k], Wfc2[k*128 + tid], acc);
        y2[tid] = lrelu(acc) * Wfc3[tid];
    }
    __syncthreads();
    if (tid == 0) {
        float acc = bfc3[0];
        for (int k = 0; k < 128; ++k) acc += y2[k];
        out[g] = acc;
    }
}

extern "C" void kernel_launch(void* const* d_in, const int* in_sizes, int n_in,
                              void* d_out, int out_size, void* d_ws, size_t ws_size,
                              hipStream_t stream)
{
    const float* x     = (const float*)d_in[0];
    const float* eattr = (const float*)d_in[1];
    const float* W1l   = (const float*)d_in[4];
    const float* b1l   = (const float*)d_in[5];
    const float* W1r   = (const float*)d_in[6];
    const float* b1r   = (const float*)d_in[7];
    const float* We1   = (const float*)d_in[8];
    const float* att1  = (const float*)d_in[9];
    const float* bias1 = (const float*)d_in[10];
    const float* W2l   = (const float*)d_in[11];
    const float* b2l   = (const float*)d_in[12];
    const float* W2r   = (const float*)d_in[13];
    const float* b2r   = (const float*)d_in[14];
    const float* We2   = (const float*)d_in[15];
    const float* att2  = (const float*)d_in[16];
    const float* bias2 = (const float*)d_in[17];
    const float* g1    = (const float*)d_in[18];
    const float* be1   = (const float*)d_in[19];
    const float* g2    = (const float*)d_in[20];
    const float* be2   = (const float*)d_in[21];
    const float* Wfc1  = (const float*)d_in[22];
    const float* bfc1  = (const float*)d_in[23];
    const float* Wfc2  = (const float*)d_in[24];
    const float* bfc2  = (const float*)d_in[25];
    const float* Wfc3  = (const float*)d_in[26];
    const float* bfc3  = (const float*)d_in[27];
    float* out = (float*)d_out;

    float* ws = (float*)d_ws;
    float* h1 = ws;                                  // NNODE*128 f32
    float* h2 = h1 + (size_t)NNODE*F1;               // NNODE*256 f32
    float* st = h2 + (size_t)NNODE*F2;               // 1536 f32 stats
    float* biascat = st + 1536;                      // 512 f32
    u16* hbf = (u16*)(biascat + 512);                // NNODE*128 bf16
    u16* xlr = hbf + (size_t)NNODE*F1;               // NNODE*512 bf16
    u16* wbt = xlr + (size_t)NNODE*F2*2;             // 512*128 bf16

    float* sum1 = st,     *ss1 = st+128, *sc1 = st+256,  *sh1 = st+384;
    float* sum2 = st+512, *ss2 = st+768, *sc2 = st+1024, *sh2 = st+1280;

    zero_kernel<<<6, 256, 0, stream>>>(st, 1536);
    prep_w<<<259, 256, 0, stream>>>(W2l, W2r, b2l, b2r, wbt, biascat);
    gat1_kernel<<<GG, 256, 0, stream>>>(x, eattr, W1l, b1l, W1r, b1r, We1, att1, bias1, h1);
    bnstats<<<288, 128, 0, stream>>>(h1, sum1, ss1, F1, 128);
    bnfin<<<1, 128, 0, stream>>>(sum1, ss1, g1, be1, sc1, sh1, F1, 1.f/NNODE);
    prep_hbf<<<NNODE*F1/4/256, 256, 0, stream>>>(h1, sc1, sh1, hbf);
    gemm2_kernel<<<(NNODE/64)*8, 256, 0, stream>>>(hbf, wbt, biascat, xlr);
    gat2_attn<<<GG, 256, 0, stream>>>(xlr, eattr, We2, att2, bias2, h2);
    bnstats<<<144, 256, 0, stream>>>(h2, sum2, ss2, F2, 256);
    bnfin<<<1, 256, 0, stream>>>(sum2, ss2, g2, be2, sc2, sh2, F2, 1.f/NNODE);
    mlp_kernel<<<GG, 256, 0, stream>>>(h2, sc2, sh2, Wfc1, bfc1, Wfc2, bfc2, Wfc3, bfc3, out);
}